// Round 12
// baseline (2091.809 us; speedup 1.0000x reference)
//
#include <hip/hip_runtime.h>
#include <hip/hip_bf16.h>
#include <hip/hip_cooperative_groups.h>
#include <stdint.h>

#define HD 128
#define GD 64
#define OUTD 16
#define NR 16   // atomic privatization replicas

typedef unsigned short u16;
typedef __attribute__((ext_vector_type(8))) short short8;
typedef __attribute__((ext_vector_type(4))) float f32x4;

__device__ __forceinline__ float bf2f(u16 u) {
  union { uint32_t i; float f; } v; v.i = ((uint32_t)u) << 16; return v.f;
}
__device__ __forceinline__ u16 f2bf(float f) {
  union { __hip_bfloat16 h; u16 u; } v; v.h = __float2bfloat16(f); return v.u;
}

__device__ __forceinline__ int seg_lower_bound(const int* b32, int N, int b) {
  int lo = 0, hi = N;
  while (lo < hi) {
    int mid = (lo + hi) >> 1;
    if (b32[mid] < b) lo = mid + 1; else hi = mid;
  }
  return lo;
}

// ---- shared MFMA core: C-tile = dinv[row] * (A@W) rows, bf16 store
__device__ __forceinline__ void gemm_core(const u16* sw, const short8* afr,
                                          int m, int qd, int orow,
                                          const float* __restrict__ dinv,
                                          u16* __restrict__ B, int N) {
  float dr[4];
#pragma unroll
  for (int r = 0; r < 4; ++r) dr[r] = (orow + r < N) ? dinv[orow + r] : 0.f;
#pragma unroll
  for (int c = 0; c < 8; ++c) {
    f32x4 acc = {0.f, 0.f, 0.f, 0.f};
    const int n = c * 16 + m;
#pragma unroll
    for (int s = 0; s < 4; ++s) {
      short8 bfr = *(const short8*)(sw + n * 136 + 32 * s + 8 * qd);
      acc = __builtin_amdgcn_mfma_f32_16x16x32_bf16(afr[s], bfr, acc, 0, 0, 0);
    }
#pragma unroll
    for (int r = 0; r < 4; ++r) {
      int rr = orow + r;
      if (rr < N) B[(size_t)rr * HD + n] = f2bf(dr[r] * acc[r]);
    }
  }
}

__device__ __forceinline__ void stage_w(const u16* __restrict__ Wt, u16* sw, int t) {
  const uint32_t* src = (const uint32_t*)Wt;
  uint32_t* dst = (uint32_t*)sw;
#pragma unroll
  for (int k = 0; k < 32; ++k) {
    int q = t + k * 256;
    int r = q >> 6;
    int u = q & 63;
    dst[r * 68 + u] = src[r * 64 + u];
  }
}

// load layer-0 A-fragment from raw x with fused NaN masking
__device__ __forceinline__ void load_afr0(const float* __restrict__ x, int arow,
                                          int qd, short8* afr, int N) {
  if (arow < N) {
    const float* xp = x + (size_t)arow * 64;
    float v0[8], v1[8];
    *(float4*)&v0[0] = *(const float4*)(xp + 8 * qd);
    *(float4*)&v0[4] = *(const float4*)(xp + 8 * qd + 4);
    *(float4*)&v1[0] = *(const float4*)(xp + 32 + 8 * qd);
    *(float4*)&v1[4] = *(const float4*)(xp + 32 + 8 * qd + 4);
#pragma unroll
    for (int j = 0; j < 8; ++j) {
      bool n0 = isnan(v0[j]), n1 = isnan(v1[j]);
      afr[0][j] = (short)f2bf(n0 ? 0.f : v0[j]);
      afr[1][j] = (short)f2bf(n1 ? 0.f : v1[j]);
      afr[2][j] = (short)(n0 ? 0x3F80 : 0);
      afr[3][j] = (short)(n1 ? 0x3F80 : 0);
    }
  } else {
    short8 z = {0, 0, 0, 0, 0, 0, 0, 0};
#pragma unroll
    for (int s = 0; s < 4; ++s) afr[s] = z;
  }
}

// ---- aggregate body (one task = one node x 8 columns)
__device__ __forceinline__ void agg_task(int task, const int* __restrict__ offs,
                                         const int2* __restrict__ csc,
                                         const u16* __restrict__ B,
                                         const float* __restrict__ dinv,
                                         const float* __restrict__ bias,
                                         const float* __restrict__ gamma,
                                         const float* __restrict__ beta,
                                         const float* __restrict__ mean,
                                         const float* __restrict__ var,
                                         int do_bn, u16* __restrict__ A) {
  int n = task >> 4;
  int f8 = (task & 15) << 3;
  float acc[8];
  short8 bu = *(const short8*)(B + (size_t)n * HD + f8);
#pragma unroll
  for (int j = 0; j < 8; ++j) acc[j] = bf2f((u16)bu[j]);

  int p = offs[n], pe = offs[n + 1];
  for (; p + 7 < pe; p += 8) {
    int2 e[8];
    short8 h[8];
#pragma unroll
    for (int u = 0; u < 8; ++u) e[u] = csc[p + u];
#pragma unroll
    for (int u = 0; u < 8; ++u) h[u] = *(const short8*)(B + (size_t)e[u].x * HD + f8);
#pragma unroll
    for (int u = 0; u < 8; ++u) {
      float w = __int_as_float(e[u].y);
#pragma unroll
      for (int j = 0; j < 8; ++j) acc[j] += w * bf2f((u16)h[u][j]);
    }
  }
  for (; p + 1 < pe; p += 2) {
    int2 e0 = csc[p], e1 = csc[p + 1];
    short8 h0 = *(const short8*)(B + (size_t)e0.x * HD + f8);
    short8 h1 = *(const short8*)(B + (size_t)e1.x * HD + f8);
    float w0 = __int_as_float(e0.y), w1 = __int_as_float(e1.y);
#pragma unroll
    for (int j = 0; j < 8; ++j)
      acc[j] += w0 * bf2f((u16)h0[j]) + w1 * bf2f((u16)h1[j]);
  }
  if (p < pe) {
    int2 e0 = csc[p];
    float w0 = __int_as_float(e0.y);
    short8 h0 = *(const short8*)(B + (size_t)e0.x * HD + f8);
#pragma unroll
    for (int j = 0; j < 8; ++j) acc[j] += w0 * bf2f((u16)h0[j]);
  }
  float dn = dinv[n];
#pragma unroll
  for (int j = 0; j < 8; ++j) acc[j] = dn * acc[j] + bias[f8 + j];
  if (do_bn) {
#pragma unroll
    for (int j = 0; j < 8; ++j) {
      float s = gamma[f8 + j] * rsqrtf(var[f8 + j] + 1e-5f);
      float v = (acc[j] - mean[f8 + j]) * s + beta[f8 + j];
      acc[j] = v > 0.f ? v : 0.f;
    }
  }
  short8 o;
#pragma unroll
  for (int j = 0; j < 8; ++j) o[j] = (short)f2bf(acc[j]);
  *(short8*)(A + (size_t)n * HD + f8) = o;
}

// ================================================================ MEGA KERNEL
struct MArgs {
  const float* x; const int* ei; const float* ea; const int* bt;
  const float *W0, *b0, *W1, *b1, *W2, *b2;
  const float *bng, *bnb, *bnm, *bnv, *mW1, *mb1, *mW2, *mb2;
  float* out;
  u16 *A, *B, *Wt;
  int2 *csc, *eidx;
  int* rank;
  float* dinv;
  int *cntR, *cursR, *offs, *b32, *bsum;
  float* sums;
  int N, E;
};

__global__ __launch_bounds__(256, 4) void mega_k(MArgs a) {
  namespace cg = cooperative_groups;
  cg::grid_group grid = cg::this_grid();
  __shared__ u16 sw[128 * 136];            // 34816 B; aliased across phases
  __shared__ int s_is64;
  const int t = threadIdx.x, bid = blockIdx.x, nb = gridDim.x;
  const int gtid = bid * 256 + t, T = nb * 256;
  const int N = a.N, E = a.E;

  // ---- P0: zero counters/sums, convert weights, detect index layout
  for (int i = gtid; i < NR * N; i += T) a.cntR[i] = 0;
  for (int i = gtid; i < GD * HD; i += T) a.sums[i] = 0.f;
  for (int i = gtid; i < 3 * HD * HD; i += T) {
    int l = i >> 14, r = i & 16383;        // HD*HD = 16384
    int n = r >> 7, k = r & 127;
    const float* W = (l == 0) ? a.W0 : (l == 1) ? a.W1 : a.W2;
    a.Wt[i] = f2bf(W[k * HD + n]);
  }
  if (t == 0) {
    int all0 = 1;
    for (int k = 1; k < 128; k += 2) all0 &= (a.ei[k] == 0);
    s_is64 = all0;
  }
  __syncthreads();
  const int is64 = s_is64;
  grid.sync();

  // ---- P1: convert + privatized count producing rank; batch convert
  for (int i = gtid; i < E; i += T) {
    int r = is64 ? a.ei[2 * i] : a.ei[i];
    int c = is64 ? a.ei[2 * (E + i)] : a.ei[E + i];
    r = (r < 0) ? 0 : (r >= N ? N - 1 : r);
    c = (c < 0) ? 0 : (c >= N ? N - 1 : c);
    a.eidx[i] = make_int2(r, c);
    int k = (i >> 8) & (NR - 1);           // pure function of i; fill uses same
    a.rank[i] = atomicAdd(&a.cntR[k * N + c], 1);
  }
  for (int i = gtid; i < N; i += T) {
    int v = is64 ? a.bt[2 * i] : a.bt[i];
    a.b32[i] = (v < 0) ? 0 : (v >= GD ? GD - 1 : v);
  }
  grid.sync();

  // ---- P2a: block-local exclusive scan (1024 nodes/block)
  const int nch = (N + 1023) >> 10;
  int* s_scan = (int*)sw;
  if (bid < nch) {
    int base = (bid << 10) + (t << 2);
    int c4[4];
#pragma unroll
    for (int j = 0; j < 4; ++j) {
      int n = base + j; int v = 0;
      if (n < N) {
#pragma unroll
        for (int k = 0; k < NR; ++k) v += a.cntR[k * N + n];
      }
      c4[j] = v;
    }
    int tot = c4[0] + c4[1] + c4[2] + c4[3];
    s_scan[t] = tot;
    __syncthreads();
    for (int off = 1; off < 256; off <<= 1) {
      int v2 = (t >= off) ? s_scan[t - off] : 0;
      __syncthreads();
      s_scan[t] += v2;
      __syncthreads();
    }
    int run = s_scan[t] - tot;
#pragma unroll
    for (int j = 0; j < 4; ++j) {
      int n = base + j;
      if (n < N) a.offs[n] = run;
      run += c4[j];
    }
    if (t == 255) a.bsum[bid] = s_scan[255];
  }
  grid.sync();

  // ---- P2b: scan the block sums (small)
  if (gtid == 0) {
    int sum = 0;
    for (int i = 0; i < nch; ++i) { int v = a.bsum[i]; a.bsum[i] = sum; sum += v; }
  }
  grid.sync();

  // ---- P2c: finalize offs + per-replica cursor bases
  for (int n = gtid; n < N; n += T) {
    int o = a.offs[n] + a.bsum[n >> 10];
    a.offs[n] = o;
    int run = o;
#pragma unroll
    for (int k = 0; k < NR; ++k) { a.cursR[k * N + n] = run; run += a.cntR[k * N + n]; }
  }
  if (gtid == 0) a.offs[N] = E;
  grid.sync();

  // ---- P3: fill CSC (atomic-free)
  for (int i = gtid; i < E; i += T) {
    int k = (i >> 8) & (NR - 1);
    int2 rc = a.eidx[i];
    float aa = a.ea[i];
    float w = isnan(aa) ? 0.f : fabsf(aa);
    int p = a.cursR[k * N + rc.y] + a.rank[i];
    a.csc[p] = make_int2(rc.x, __float_as_int(w));
  }
  grid.sync();

  // ---- P4: deg -> dinv
  for (int n = gtid; n < N; n += T) {
    int p = a.offs[n], pe = a.offs[n + 1];
    float s = 0.f;
    for (; p < pe; ++p) s += __int_as_float(a.csc[p].y);
    a.dinv[n] = rsqrtf(s + 1.0f);
  }
  grid.sync();

  // ---- P5..P10: 3 x (GEMM -> aggregate)
  const int w = t >> 6, lane = t & 63, m = lane & 15, qd = lane >> 4;
  for (int layer = 0; layer < 3; ++layer) {
    stage_w(a.Wt + layer * HD * HD, sw, t);
    __syncthreads();
    for (int tile = bid; tile * 64 < N; tile += nb) {
      int arow = tile * 64 + w * 16 + m;
      short8 afr[4];
      if (layer == 0) {
        load_afr0(a.x, arow, qd, afr, N);
      } else if (arow < N) {
        const short8* ap = (const short8*)(a.A + (size_t)arow * HD);
#pragma unroll
        for (int s = 0; s < 4; ++s) afr[s] = ap[4 * s + qd];
      } else {
        short8 z = {0, 0, 0, 0, 0, 0, 0, 0};
#pragma unroll
        for (int s = 0; s < 4; ++s) afr[s] = z;
      }
      int orow = tile * 64 + w * 16 + qd * 4;
      gemm_core(sw, afr, m, qd, orow, a.dinv, a.B, N);
    }
    grid.sync();
    const float* bias = (layer == 0) ? a.b0 : (layer == 1) ? a.b1 : a.b2;
    int do_bn = (layer < 2);
    for (int task = gtid; task < N * 16; task += T)
      agg_task(task, a.offs, a.csc, a.B, a.dinv, bias,
               a.bng, a.bnb, a.bnm, a.bnv, do_bn, a.A);
    grid.sync();
  }

  // ---- P11: pool (64 graphs x 32 chunks)
  {
    int* sbp = (int*)sw;
    for (int bt2 = bid; bt2 < GD * 32; bt2 += nb) {
      int b = bt2 >> 5, ch = bt2 & 31;
      if (t < 2) sbp[t] = seg_lower_bound(a.b32, N, b + t);
      __syncthreads();
      int s = sbp[0], e = sbp[1];
      __syncthreads();
      int len = e - s;
      if (t < 128 && len > 0) {
        int chsz = (len + 31) >> 5;
        int lo = s + ch * chsz;
        int hi = lo + chsz; if (hi > e) hi = e;
        if (lo < hi) {
          float a0 = 0.f, a1 = 0.f, a2 = 0.f, a3 = 0.f;
          int n = lo;
          for (; n + 3 < hi; n += 4) {
            a0 += bf2f(a.A[(size_t)(n + 0) * HD + t]);
            a1 += bf2f(a.A[(size_t)(n + 1) * HD + t]);
            a2 += bf2f(a.A[(size_t)(n + 2) * HD + t]);
            a3 += bf2f(a.A[(size_t)(n + 3) * HD + t]);
          }
          for (; n < hi; ++n) a0 += bf2f(a.A[(size_t)n * HD + t]);
          unsafeAtomicAdd(&a.sums[b * HD + t], (a0 + a1) + (a2 + a3));
        }
      }
    }
  }
  grid.sync();

  // ---- P12: MLP head
  if (bid < GD) {
    float* sg = (float*)sw;
    float* st = sg + 128;
    int* sb2 = (int*)(st + 128);
    if (t < 2) sb2[t] = seg_lower_bound(a.b32, N, bid + t);
    __syncthreads();
    int cnt = sb2[1] - sb2[0];
    float inv = 1.0f / (float)(cnt > 0 ? cnt : 1);
    if (t < 128) sg[t] = a.sums[bid * HD + t] * inv;
    __syncthreads();
    if (t < 128) {
      float s = a.mb1[t];
#pragma unroll 4
      for (int i = 0; i < 128; ++i) s += sg[i] * a.mW1[i * 128 + t];
      st[t] = 0.5f * s * (1.0f + erff(s * 0.70710678118654752f));
    }
    __syncthreads();
    if (t < OUTD) {
      float o = a.mb2[t];
#pragma unroll 4
      for (int k = 0; k < 128; ++k) o += st[k] * a.mW2[k * OUTD + t];
      a.out[bid * OUTD + t] = o;
    }
  }
}

// ================================================================ FALLBACK
// (round-11 multi-kernel path, used only if cooperative launch errors)

__global__ __launch_bounds__(256)
void convert_count_k(const int* __restrict__ ei, const int* __restrict__ bt,
                     int2* __restrict__ eidx, int* __restrict__ b32,
                     int* __restrict__ cntR, int* __restrict__ rank,
                     int E, int N) {
  __shared__ int s_is64;
  if (threadIdx.x == 0) {
    int all0 = 1;
    for (int k = 1; k < 128; k += 2) all0 &= (ei[k] == 0);
    s_is64 = all0;
  }
  __syncthreads();
  int is64 = s_is64;
  int i = blockIdx.x * 256 + threadIdx.x;
  if (i < E) {
    int r = is64 ? ei[2 * i] : ei[i];
    int c = is64 ? ei[2 * (E + i)] : ei[E + i];
    r = (r < 0) ? 0 : (r >= N ? N - 1 : r);
    c = (c < 0) ? 0 : (c >= N ? N - 1 : c);
    eidx[i] = make_int2(r, c);
    int k = (i >> 8) & (NR - 1);
    rank[i] = atomicAdd(&cntR[k * N + c], 1);
  }
  if (i < N) {
    int v = is64 ? bt[2 * i] : bt[i];
    b32[i] = (v < 0) ? 0 : (v >= GD ? GD - 1 : v);
  }
}

__global__ void scan1_k(const int* __restrict__ cntR, int* __restrict__ offs,
                        int* __restrict__ bsum, int Np, int N) {
  __shared__ int s[1024];
  int i = blockIdx.x * 1024 + threadIdx.x;
  int v = 0;
  if (i < Np) {
#pragma unroll
    for (int k = 0; k < NR; ++k) v += cntR[k * N + i];
  }
  s[threadIdx.x] = v;
  __syncthreads();
  for (int off = 1; off < 1024; off <<= 1) {
    int t = (threadIdx.x >= off) ? s[threadIdx.x - off] : 0;
    __syncthreads();
    s[threadIdx.x] += t;
    __syncthreads();
  }
  if (i < Np) offs[i] = s[threadIdx.x] - v;
  if (threadIdx.x == 1023) bsum[blockIdx.x] = s[1023];
}
__global__ void scan2_k(int* bsum, int nb) {
  if (threadIdx.x == 0 && blockIdx.x == 0) {
    int sum = 0;
    for (int i = 0; i < nb; ++i) { int v = bsum[i]; bsum[i] = sum; sum += v; }
  }
}
__global__ void scan3curs_k(int* __restrict__ offs, const int* __restrict__ bsum,
                            const int* __restrict__ cntR, int* __restrict__ cursR,
                            int Np, int E, int N) {
  int n = blockIdx.x * 256 + threadIdx.x;
  if (n < Np) {
    int o = offs[n] + bsum[n >> 10];
    offs[n] = o;
    int run = o;
#pragma unroll
    for (int k = 0; k < NR; ++k) { cursR[k * N + n] = run; run += cntR[k * N + n]; }
  }
  if (n == 0) offs[Np] = E;
}

__global__ __launch_bounds__(256)
void fill_k(const int2* __restrict__ eidx, const float* __restrict__ ea,
            const int* __restrict__ cursR, const int* __restrict__ rank,
            int2* __restrict__ csc, int E, int N) {
  int e = blockIdx.x * 256 + threadIdx.x;
  if (e >= E) return;
  int k = (e >> 8) & (NR - 1);
  int2 rc = eidx[e];
  float a = ea[e];
  float w = isnan(a) ? 0.f : fabsf(a);
  int p = cursR[k * N + rc.y] + rank[e];
  csc[p] = make_int2(rc.x, __float_as_int(w));
}

__global__ void deg_k(const int* __restrict__ offs, const int2* __restrict__ csc,
                      float* __restrict__ dinv, int N) {
  int n = blockIdx.x * 256 + threadIdx.x;
  if (n >= N) return;
  int p = offs[n], pe = offs[n + 1];
  float s = 0.f;
  for (; p < pe; ++p) s += __int_as_float(csc[p].y);
  dinv[n] = rsqrtf(s + 1.0f);
}

__global__ void convw3_k(const float* __restrict__ W0, const float* __restrict__ W1,
                         const float* __restrict__ W2, u16* __restrict__ Wt) {
  int i = blockIdx.x * 256 + threadIdx.x;
  if (i >= 3 * HD * HD) return;
  int l = i >> 14, r = i & 16383;
  int n = r >> 7, k = r & 127;
  const float* W = (l == 0) ? W0 : (l == 1) ? W1 : W2;
  Wt[i] = f2bf(W[k * HD + n]);
}

__global__ void zero_cs_k(int* cntR, float* sums, int nc, int ns) {
  int i = blockIdx.x * 256 + threadIdx.x;
  if (i < nc) cntR[i] = 0;
  if (i < ns) sums[i] = 0.f;
}

__global__ __launch_bounds__(256)
void gemm0_k(const float* __restrict__ x, const u16* __restrict__ Wt,
             const float* __restrict__ dinv, u16* __restrict__ B, int N) {
  __shared__ u16 sw[128 * 136];
  const int t = threadIdx.x;
  stage_w(Wt, sw, t);
  __syncthreads();
  const int w = t >> 6, lane = t & 63, m = lane & 15, qd = lane >> 4;
  const int arow = blockIdx.x * 64 + w * 16 + m;
  short8 afr[4];
  load_afr0(x, arow, qd, afr, N);
  const int orow = blockIdx.x * 64 + w * 16 + qd * 4;
  gemm_core(sw, afr, m, qd, orow, dinv, B, N);
}

__global__ __launch_bounds__(256)
void gemm_k(const u16* __restrict__ A, const u16* __restrict__ Wt,
            const float* __restrict__ dinv, u16* __restrict__ B, int N) {
  __shared__ u16 sw[128 * 136];
  const int t = threadIdx.x;
  stage_w(Wt, sw, t);
  __syncthreads();
  const int w = t >> 6, lane = t & 63, m = lane & 15, qd = lane >> 4;
  const int arow = blockIdx.x * 64 + w * 16 + m;
  short8 afr[4];
  if (arow < N) {
    const short8* ap = (const short8*)(A + (size_t)arow * HD);
#pragma unroll
    for (int s = 0; s < 4; ++s) afr[s] = ap[4 * s + qd];
  } else {
    short8 z = {0, 0, 0, 0, 0, 0, 0, 0};
#pragma unroll
    for (int s = 0; s < 4; ++s) afr[s] = z;
  }
  const int orow = blockIdx.x * 64 + w * 16 + qd * 4;
  gemm_core(sw, afr, m, qd, orow, dinv, B, N);
}

__global__ __launch_bounds__(256)
void aggregate_k(const int* __restrict__ offs, const int2* __restrict__ csc,
                 const u16* __restrict__ B, const float* __restrict__ dinv,
                 const float* __restrict__ bias, const float* __restrict__ gamma,
                 const float* __restrict__ beta, const float* __restrict__ mean,
                 const float* __restrict__ var, int do_bn,
                 u16* __restrict__ A, int N) {
  int task = blockIdx.x * 256 + threadIdx.x;
  if (task >= N * 16) return;
  agg_task(task, offs, csc, B, dinv, bias, gamma, beta, mean, var, do_bn, A);
}

__global__ __launch_bounds__(128)
void pool1_k(const u16* __restrict__ A, const int* __restrict__ b32,
             float* __restrict__ sums, int N) {
  __shared__ int sb[2];
  int b = blockIdx.y;
  if (threadIdx.x < 2) sb[threadIdx.x] = seg_lower_bound(b32, N, b + threadIdx.x);
  __syncthreads();
  int s = sb[0], e = sb[1];
  int len = e - s;
  if (len <= 0) return;
  int nch = gridDim.x;
  int ch = (len + nch - 1) / nch;
  int lo = s + blockIdx.x * ch;
  int hi = lo + ch; if (hi > e) hi = e;
  if (lo >= hi) return;
  int j = threadIdx.x;
  float a0 = 0.f, a1 = 0.f, a2 = 0.f, a3 = 0.f;
  int n = lo;
  for (; n + 3 < hi; n += 4) {
    a0 += bf2f(A[(size_t)(n + 0) * HD + j]);
    a1 += bf2f(A[(size_t)(n + 1) * HD + j]);
    a2 += bf2f(A[(size_t)(n + 2) * HD + j]);
    a3 += bf2f(A[(size_t)(n + 3) * HD + j]);
  }
  for (; n < hi; ++n) a0 += bf2f(A[(size_t)n * HD + j]);
  unsafeAtomicAdd(&sums[b * HD + j], (a0 + a1) + (a2 + a3));
}

__global__ __launch_bounds__(128)
void mlp_k(const float* __restrict__ sums, const int* __restrict__ b32,
           const float* __restrict__ mW1, const float* __restrict__ mb1,
           const float* __restrict__ mW2, const float* __restrict__ mb2,
           float* __restrict__ out, int N) {
  __shared__ float sg[128];
  __shared__ float st[128];
  __shared__ int sb[2];
  int b = blockIdx.x, j = threadIdx.x;
  if (j < 2) sb[j] = seg_lower_bound(b32, N, b + j);
  __syncthreads();
  int cnt = sb[1] - sb[0];
  float inv = 1.0f / (float)(cnt > 0 ? cnt : 1);
  sg[j] = sums[b * HD + j] * inv;
  __syncthreads();
  float s = mb1[j];
#pragma unroll 4
  for (int i = 0; i < 128; ++i) s += sg[i] * mW1[i * 128 + j];
  st[j] = 0.5f * s * (1.0f + erff(s * 0.70710678118654752f));
  __syncthreads();
  if (j < OUTD) {
    float o = mb2[j];
#pragma unroll 4
    for (int k = 0; k < 128; ++k) o += st[k] * mW2[k * OUTD + j];
    out[b * OUTD + j] = o;
  }
}

// ---------------------------------------------------------------- launch
extern "C" void kernel_launch(void* const* d_in, const int* in_sizes, int n_in,
                              void* d_out, int out_size, void* d_ws, size_t ws_size,
                              hipStream_t stream) {
  const float* x   = (const float*)d_in[0];
  const int* ei    = (const int*)d_in[1];
  const float* ea  = (const float*)d_in[2];
  const int* bt    = (const int*)d_in[3];
  const float* W0  = (const float*)d_in[4];
  const float* b0  = (const float*)d_in[5];
  const float* W1  = (const float*)d_in[6];
  const float* b1  = (const float*)d_in[7];
  const float* W2  = (const float*)d_in[8];
  const float* b2  = (const float*)d_in[9];
  const float* bng = (const float*)d_in[10];
  const float* bnb = (const float*)d_in[11];
  const float* bnm = (const float*)d_in[12];
  const float* bnv = (const float*)d_in[13];
  const float* mW1 = (const float*)d_in[14];
  const float* mb1 = (const float*)d_in[15];
  const float* mW2 = (const float*)d_in[16];
  const float* mb2 = (const float*)d_in[17];
  float* out = (float*)d_out;

  const int N = in_sizes[0] / 64;      // 50000
  const int E = in_sizes[2];           // 800000

  char* ws = (char*)d_ws;
  size_t NB2 = (size_t)N * HD * 2;
  u16* A       = (u16*)(ws);
  u16* B       = (u16*)(ws + NB2);
  char* q      = ws + 2 * NB2;
  int*   cntR  = (int*)q;              q += (size_t)NR * N * 4;
  float* sums  = (float*)q;            q += GD * HD * 4;
  u16* Wt      = (u16*)q;              q += (size_t)3 * HD * HD * 2;
  int2* csc    = (int2*)q;             q += (size_t)E * 8;
  int2* eidx   = (int2*)q;             q += (size_t)E * 8;
  int*  rank   = (int*)q;              q += (size_t)E * 4;
  float* dinv  = (float*)q;            q += (size_t)N * 4;
  int*   cursR = (int*)q;              q += (size_t)NR * N * 4;
  int*   offs  = (int*)q;              q += (size_t)(N + 2) * 4;
  int*   b32   = (int*)q;              q += (size_t)N * 4;
  int*   bsum  = (int*)q;              q += 64 * 4;

  MArgs margs;
  margs.x = x; margs.ei = ei; margs.ea = ea; margs.bt = bt;
  margs.W0 = W0; margs.b0 = b0; margs.W1 = W1; margs.b1 = b1;
  margs.W2 = W2; margs.b2 = b2;
  margs.bng = bng; margs.bnb = bnb; margs.bnm = bnm; margs.bnv = bnv;
  margs.mW1 = mW1; margs.mb1 = mb1; margs.mW2 = mW2; margs.mb2 = mb2;
  margs.out = out;
  margs.A = A; margs.B = B; margs.Wt = Wt;
  margs.csc = csc; margs.eidx = eidx; margs.rank = rank; margs.dinv = dinv;
  margs.cntR = cntR; margs.cursR = cursR; margs.offs = offs;
  margs.b32 = b32; margs.bsum = bsum; margs.sums = sums;
  margs.N = N; margs.E = E;

  void* kargs[] = { &margs };
  hipError_t err = hipLaunchCooperativeKernel((const void*)mega_k, dim3(1024),
                                              dim3(256), kargs, 0, stream);
  if (err == hipSuccess) return;
  (void)hipGetLastError();   // clear sticky error; run fallback path

  dim3 blk(256);
  int gE  = (E + 255) / 256;
  int gN  = (N + 255) / 256;
  int nb1024 = (N + 1023) / 1024;
  int nz = NR * N > GD * HD ? NR * N : GD * HD;

  zero_cs_k<<<(nz + 255) / 256, blk, 0, stream>>>(cntR, sums, NR * N, GD * HD);
  convert_count_k<<<gE, blk, 0, stream>>>(ei, bt, eidx, b32, cntR, rank, E, N);
  scan1_k<<<nb1024, 1024, 0, stream>>>(cntR, offs, bsum, N, N);
  scan2_k<<<1, 64, 0, stream>>>(bsum, nb1024);
  scan3curs_k<<<gN, blk, 0, stream>>>(offs, bsum, cntR, cursR, N, E, N);
  fill_k<<<gE, blk, 0, stream>>>(eidx, ea, cursR, rank, csc, E, N);
  deg_k<<<gN, blk, 0, stream>>>(offs, csc, dinv, N);
  convw3_k<<<(3 * HD * HD + 255) / 256, blk, 0, stream>>>(W0, W1, W2, Wt);

  int gGemm = (N + 63) / 64;
  int gAgg  = (N * 16 + 255) / 256;

  gemm0_k<<<gGemm, 256, 0, stream>>>(x, Wt, dinv, B, N);
  aggregate_k<<<gAgg, blk, 0, stream>>>(offs, csc, B, dinv, b0,
                                        bng, bnb, bnm, bnv, 1, A, N);
  gemm_k<<<gGemm, 256, 0, stream>>>(A, Wt + HD * HD, dinv, B, N);
  aggregate_k<<<gAgg, blk, 0, stream>>>(offs, csc, B, dinv, b1,
                                        bng, bnb, bnm, bnv, 1, A, N);
  gemm_k<<<gGemm, 256, 0, stream>>>(A, Wt + 2 * HD * HD, dinv, B, N);
  aggregate_k<<<gAgg, blk, 0, stream>>>(offs, csc, B, dinv, b2,
                                        bng, bnb, bnm, bnv, 0, A, N);

  dim3 pgrid(32, GD);
  pool1_k<<<pgrid, 128, 0, stream>>>(A, b32, sums, N);
  mlp_k<<<GD, 128, 0, stream>>>(sums, b32, mW1, mb1, mW2, mb2, out, N);
}

// Round 13
// 328.553 us; speedup vs baseline: 6.3667x; 6.3667x over previous
//
#include <hip/hip_runtime.h>
#include <hip/hip_bf16.h>
#include <stdint.h>

#define HD 128
#define GD 64
#define OUTD 16
#define NR 16   // atomic privatization replicas

typedef unsigned short u16;
typedef __attribute__((ext_vector_type(8))) short short8;
typedef __attribute__((ext_vector_type(4))) float f32x4;

__device__ __forceinline__ float bf2f(u16 u) {
  union { uint32_t i; float f; } v; v.i = ((uint32_t)u) << 16; return v.f;
}
__device__ __forceinline__ u16 f2bf(float f) {
  union { __hip_bfloat16 h; u16 u; } v; v.h = __float2bfloat16(f); return v.u;
}

// Fused: layout-detect + index convert + batch convert + privatized count
// producing per-edge rank.  k = blockIdx & (NR-1); fill_k MUST use same mapping.
__global__ __launch_bounds__(256)
void convert_count_k(const int* __restrict__ ei, const int* __restrict__ bt,
                     int2* __restrict__ eidx, int* __restrict__ b32,
                     int* __restrict__ cntR, int* __restrict__ rank,
                     int E, int N) {
  __shared__ int s_is64;
  if (threadIdx.x == 0) {
    int all0 = 1;
    for (int k = 1; k < 128; k += 2) all0 &= (ei[k] == 0);
    s_is64 = all0;
  }
  __syncthreads();
  int is64 = s_is64;
  int i = blockIdx.x * 256 + threadIdx.x;
  if (i < E) {
    int r = is64 ? ei[2 * i] : ei[i];
    int c = is64 ? ei[2 * (E + i)] : ei[E + i];
    r = (r < 0) ? 0 : (r >= N ? N - 1 : r);
    c = (c < 0) ? 0 : (c >= N ? N - 1 : c);
    eidx[i] = make_int2(r, c);
    int k = blockIdx.x & (NR - 1);
    rank[i] = atomicAdd(&cntR[k * N + c], 1);
  }
  if (i < N) {
    int v = is64 ? bt[2 * i] : bt[i];
    b32[i] = (v < 0) ? 0 : (v >= GD ? GD - 1 : v);
  }
}

// ---- scan; scan1 sums the NR replicas inline
__global__ void scan1_k(const int* __restrict__ cntR, int* __restrict__ offs,
                        int* __restrict__ bsum, int Np, int N) {
  __shared__ int s[1024];
  int i = blockIdx.x * 1024 + threadIdx.x;
  int v = 0;
  if (i < Np) {
#pragma unroll
    for (int k = 0; k < NR; ++k) v += cntR[k * N + i];
  }
  s[threadIdx.x] = v;
  __syncthreads();
  for (int off = 1; off < 1024; off <<= 1) {
    int t = (threadIdx.x >= off) ? s[threadIdx.x - off] : 0;
    __syncthreads();
    s[threadIdx.x] += t;
    __syncthreads();
  }
  if (i < Np) offs[i] = s[threadIdx.x] - v;
  if (threadIdx.x == 1023) bsum[blockIdx.x] = s[1023];
}

// fused: prefix the block sums (thread 0, <=49 adds), finalize offs,
// emit per-replica cursor bases, offs[N]=E
__global__ void scan3curs_k(int* __restrict__ offs, const int* __restrict__ bsum,
                            const int* __restrict__ cntR, int* __restrict__ cursR,
                            int Np, int E, int N, int nb1024) {
  __shared__ int s_pref;
  int n = blockIdx.x * 256 + threadIdx.x;
  if (threadIdx.x == 0) {
    int chunk = (blockIdx.x * 256) >> 10;   // all 256 nodes in a block share one
    int sum = 0;                            // 1024-chunk (256 | 1024)
    for (int i = 0; i < chunk; ++i) sum += bsum[i];
    s_pref = sum;
  }
  __syncthreads();
  if (n < Np) {
    int o = offs[n] + s_pref;
    offs[n] = o;
    int run = o;
#pragma unroll
    for (int k = 0; k < NR; ++k) { cursR[k * N + n] = run; run += cntR[k * N + n]; }
  }
  if (n == 0) offs[Np] = E;
}

// fill CSC — atomic-free: p = cursR[k][col] + rank[e]; one 8B scattered store.
// csc[p] = {row, bits(|w|)}  (|w| stays raw; dinv factored into gemm epilogue)
__global__ __launch_bounds__(256)
void fill_k(const int2* __restrict__ eidx, const float* __restrict__ ea,
            const int* __restrict__ cursR, const int* __restrict__ rank,
            int2* __restrict__ csc, int E, int N) {
  int e = blockIdx.x * 256 + threadIdx.x;
  if (e >= E) return;
  int k = blockIdx.x & (NR - 1);
  int2 rc = eidx[e];
  float a = ea[e];
  float w = isnan(a) ? 0.f : fabsf(a);
  int p = cursR[k * N + rc.y] + rank[e];
  csc[p] = make_int2(rc.x, __float_as_int(w));
}

// dinv[n] = rsqrt(sum of in-weights + 1)
__global__ void deg_k(const int* __restrict__ offs, const int2* __restrict__ csc,
                      float* __restrict__ dinv, int N) {
  int n = blockIdx.x * 256 + threadIdx.x;
  if (n >= N) return;
  int p = offs[n], pe = offs[n + 1];
  float s = 0.f;
  for (; p < pe; ++p) s += __int_as_float(csc[p].y);
  dinv[n] = rsqrtf(s + 1.0f);
}

// transpose+convert all 3 weights: Wt[l][n][k] = bf16(W_l[k][n])
__global__ void convw3_k(const float* __restrict__ W0, const float* __restrict__ W1,
                         const float* __restrict__ W2, u16* __restrict__ Wt) {
  int i = blockIdx.x * 256 + threadIdx.x;
  if (i >= 3 * HD * HD) return;
  int l = i / (HD * HD);
  int r = i - l * (HD * HD);
  int n = r >> 7, k = r & 127;
  const float* W = (l == 0) ? W0 : (l == 1) ? W1 : W2;
  Wt[i] = f2bf(W[k * HD + n]);
}

// ---- shared MFMA core: C-tile = dinv[row] * (A@W) rows, bf16 store
__device__ __forceinline__ void gemm_core(const u16* sw, const short8* afr,
                                          int m, int qd, int orow,
                                          const float* __restrict__ dinv,
                                          u16* __restrict__ B, int N) {
  float dr[4];
#pragma unroll
  for (int r = 0; r < 4; ++r) dr[r] = (orow + r < N) ? dinv[orow + r] : 0.f;
#pragma unroll
  for (int c = 0; c < 8; ++c) {
    f32x4 acc = {0.f, 0.f, 0.f, 0.f};
    const int n = c * 16 + m;
#pragma unroll
    for (int s = 0; s < 4; ++s) {
      short8 bfr = *(const short8*)(sw + n * 136 + 32 * s + 8 * qd);
      acc = __builtin_amdgcn_mfma_f32_16x16x32_bf16(afr[s], bfr, acc, 0, 0, 0);
    }
#pragma unroll
    for (int r = 0; r < 4; ++r) {
      int rr = orow + r;
      if (rr < N) B[(size_t)rr * HD + n] = f2bf(dr[r] * acc[r]);
    }
  }
}

__device__ __forceinline__ void stage_w(const u16* __restrict__ Wt, u16* sw, int t) {
  const uint32_t* src = (const uint32_t*)Wt;
  uint32_t* dst = (uint32_t*)sw;
#pragma unroll
  for (int k = 0; k < 32; ++k) {
    int q = t + k * 256;
    int r = q >> 6;
    int u = q & 63;
    dst[r * 68 + u] = src[r * 64 + u];
  }
}

// layer-0 GEMM with fused h0 construction: reads x[N,64] fp32 directly.
__global__ __launch_bounds__(256)
void gemm0_k(const float* __restrict__ x, const u16* __restrict__ Wt,
             const float* __restrict__ dinv, u16* __restrict__ B, int N) {
  __shared__ u16 sw[128 * 136];
  const int t = threadIdx.x;
  stage_w(Wt, sw, t);
  __syncthreads();
  const int w = t >> 6;
  const int lane = t & 63;
  const int m = lane & 15;
  const int qd = lane >> 4;
  const int arow = blockIdx.x * 64 + w * 16 + m;
  short8 afr[4];
  if (arow < N) {
    const float* xp = x + (size_t)arow * 64;
    float v0[8], v1[8];
    *(float4*)&v0[0] = *(const float4*)(xp + 8 * qd);
    *(float4*)&v0[4] = *(const float4*)(xp + 8 * qd + 4);
    *(float4*)&v1[0] = *(const float4*)(xp + 32 + 8 * qd);
    *(float4*)&v1[4] = *(const float4*)(xp + 32 + 8 * qd + 4);
#pragma unroll
    for (int j = 0; j < 8; ++j) {
      bool n0 = isnan(v0[j]), n1 = isnan(v1[j]);
      afr[0][j] = (short)f2bf(n0 ? 0.f : v0[j]);
      afr[1][j] = (short)f2bf(n1 ? 0.f : v1[j]);
      afr[2][j] = (short)(n0 ? 0x3F80 : 0);
      afr[3][j] = (short)(n1 ? 0x3F80 : 0);
    }
  } else {
    short8 z = {0, 0, 0, 0, 0, 0, 0, 0};
#pragma unroll
    for (int s = 0; s < 4; ++s) afr[s] = z;
  }
  const int orow = blockIdx.x * 64 + w * 16 + qd * 4;
  gemm_core(sw, afr, m, qd, orow, dinv, B, N);
}

// generic GEMM: B = dinv-scaled rows of (A @ W), A bf16
__global__ __launch_bounds__(256)
void gemm_k(const u16* __restrict__ A, const u16* __restrict__ Wt,
            const float* __restrict__ dinv, u16* __restrict__ B, int N) {
  __shared__ u16 sw[128 * 136];
  const int t = threadIdx.x;
  stage_w(Wt, sw, t);
  __syncthreads();
  const int w = t >> 6;
  const int lane = t & 63;
  const int m = lane & 15;
  const int qd = lane >> 4;
  const int arow = blockIdx.x * 64 + w * 16 + m;
  short8 afr[4];
  if (arow < N) {
    const short8* ap = (const short8*)(A + (size_t)arow * HD);
#pragma unroll
    for (int s = 0; s < 4; ++s) afr[s] = ap[4 * s + qd];
  } else {
    short8 z = {0, 0, 0, 0, 0, 0, 0, 0};
#pragma unroll
    for (int s = 0; s < 4; ++s) afr[s] = z;
  }
  const int orow = blockIdx.x * 64 + w * 16 + qd * 4;
  gemm_core(sw, afr, m, qd, orow, dinv, B, N);
}

// Fused: A[n] = BN?ReLU( dinv[n]*(C[n] + sum_in w*C[row]) + bias )
// C = dinv-prescaled GEMM output. 16 lanes/node, 16B gathers, unroll x8.
__global__ __launch_bounds__(256)
void aggregate_k(const int* __restrict__ offs, const int2* __restrict__ csc,
                 const u16* __restrict__ B, const float* __restrict__ dinv,
                 const float* __restrict__ bias, const float* __restrict__ gamma,
                 const float* __restrict__ beta, const float* __restrict__ mean,
                 const float* __restrict__ var, int do_bn,
                 u16* __restrict__ A, int N) {
  int tid = blockIdx.x * 256 + threadIdx.x;
  int n = tid >> 4;
  if (n >= N) return;
  int f8 = (tid & 15) << 3;
  float acc[8];
  short8 bu = *(const short8*)(B + (size_t)n * HD + f8);
#pragma unroll
  for (int j = 0; j < 8; ++j) acc[j] = bf2f((u16)bu[j]);   // self term C[n]

  int p = offs[n], pe = offs[n + 1];
  for (; p + 7 < pe; p += 8) {
    int2 e[8];
    short8 h[8];
#pragma unroll
    for (int u = 0; u < 8; ++u) e[u] = csc[p + u];
#pragma unroll
    for (int u = 0; u < 8; ++u) h[u] = *(const short8*)(B + (size_t)e[u].x * HD + f8);
#pragma unroll
    for (int u = 0; u < 8; ++u) {
      float w = __int_as_float(e[u].y);
#pragma unroll
      for (int j = 0; j < 8; ++j) acc[j] += w * bf2f((u16)h[u][j]);
    }
  }
  for (; p + 1 < pe; p += 2) {
    int2 e0 = csc[p], e1 = csc[p + 1];
    short8 h0 = *(const short8*)(B + (size_t)e0.x * HD + f8);
    short8 h1 = *(const short8*)(B + (size_t)e1.x * HD + f8);
    float w0 = __int_as_float(e0.y), w1 = __int_as_float(e1.y);
#pragma unroll
    for (int j = 0; j < 8; ++j)
      acc[j] += w0 * bf2f((u16)h0[j]) + w1 * bf2f((u16)h1[j]);
  }
  if (p < pe) {
    int2 e0 = csc[p];
    float w0 = __int_as_float(e0.y);
    short8 h0 = *(const short8*)(B + (size_t)e0.x * HD + f8);
#pragma unroll
    for (int j = 0; j < 8; ++j) acc[j] += w0 * bf2f((u16)h0[j]);
  }
  float dn = dinv[n];
#pragma unroll
  for (int j = 0; j < 8; ++j) acc[j] = dn * acc[j] + bias[f8 + j];
  if (do_bn) {
#pragma unroll
    for (int j = 0; j < 8; ++j) {
      float s = gamma[f8 + j] * rsqrtf(var[f8 + j] + 1e-5f);
      float v = (acc[j] - mean[f8 + j]) * s + beta[f8 + j];
      acc[j] = v > 0.f ? v : 0.f;
    }
  }
  short8 o;
#pragma unroll
  for (int j = 0; j < 8; ++j) o[j] = (short)f2bf(acc[j]);
  *(short8*)(A + (size_t)n * HD + f8) = o;
}

__device__ __forceinline__ int seg_lower_bound(const int* b32, int N, int b) {
  int lo = 0, hi = N;
  while (lo < hi) {
    int mid = (lo + hi) >> 1;
    if (b32[mid] < b) lo = mid + 1; else hi = mid;
  }
  return lo;
}

// two-stage mean pool, stage 1 (bf16 input); segment bounds found inline
__global__ __launch_bounds__(128)
void pool1_k(const u16* __restrict__ A, const int* __restrict__ b32,
             float* __restrict__ sums, int N) {
  __shared__ int sb[2];
  int b = blockIdx.y;
  if (threadIdx.x < 2) sb[threadIdx.x] = seg_lower_bound(b32, N, b + threadIdx.x);
  __syncthreads();
  int s = sb[0], e = sb[1];
  int len = e - s;
  if (len <= 0) return;
  int nch = gridDim.x;
  int ch = (len + nch - 1) / nch;
  int lo = s + blockIdx.x * ch;
  int hi = lo + ch; if (hi > e) hi = e;
  if (lo >= hi) return;
  int j = threadIdx.x;
  float a0 = 0.f, a1 = 0.f, a2 = 0.f, a3 = 0.f;
  int n = lo;
  for (; n + 3 < hi; n += 4) {
    a0 += bf2f(A[(size_t)(n + 0) * HD + j]);
    a1 += bf2f(A[(size_t)(n + 1) * HD + j]);
    a2 += bf2f(A[(size_t)(n + 2) * HD + j]);
    a3 += bf2f(A[(size_t)(n + 3) * HD + j]);
  }
  for (; n < hi; ++n) a0 += bf2f(A[(size_t)n * HD + j]);
  unsafeAtomicAdd(&sums[b * HD + j], (a0 + a1) + (a2 + a3));
}

// out = gelu((sums/cnt)@mW1+mb1) @ mW2 + mb2
__global__ __launch_bounds__(128)
void mlp_k(const float* __restrict__ sums, const int* __restrict__ b32,
           const float* __restrict__ mW1, const float* __restrict__ mb1,
           const float* __restrict__ mW2, const float* __restrict__ mb2,
           float* __restrict__ out, int N) {
  __shared__ float sg[128];
  __shared__ float st[128];
  __shared__ int sb[2];
  int b = blockIdx.x, j = threadIdx.x;
  if (j < 2) sb[j] = seg_lower_bound(b32, N, b + j);
  __syncthreads();
  int cnt = sb[1] - sb[0];
  float inv = 1.0f / (float)(cnt > 0 ? cnt : 1);
  sg[j] = sums[b * HD + j] * inv;
  __syncthreads();
  float s = mb1[j];
#pragma unroll 4
  for (int i = 0; i < 128; ++i) s += sg[i] * mW1[i * 128 + j];
  float ge = 0.5f * s * (1.0f + erff(s * 0.70710678118654752f));
  st[j] = ge;
  __syncthreads();
  if (j < OUTD) {
    float o = mb2[j];
#pragma unroll 4
    for (int k = 0; k < 128; ++k) o += st[k] * mW2[k * OUTD + j];
    out[b * OUTD + j] = o;
  }
}

// ---------------------------------------------------------------- launch
extern "C" void kernel_launch(void* const* d_in, const int* in_sizes, int n_in,
                              void* d_out, int out_size, void* d_ws, size_t ws_size,
                              hipStream_t stream) {
  const float* x   = (const float*)d_in[0];
  const int* ei    = (const int*)d_in[1];
  const float* ea  = (const float*)d_in[2];
  const int* bt    = (const int*)d_in[3];
  const float* W0  = (const float*)d_in[4];
  const float* b0  = (const float*)d_in[5];
  const float* W1  = (const float*)d_in[6];
  const float* b1  = (const float*)d_in[7];
  const float* W2  = (const float*)d_in[8];
  const float* b2  = (const float*)d_in[9];
  const float* bng = (const float*)d_in[10];
  const float* bnb = (const float*)d_in[11];
  const float* bnm = (const float*)d_in[12];
  const float* bnv = (const float*)d_in[13];
  const float* mW1 = (const float*)d_in[14];
  const float* mb1 = (const float*)d_in[15];
  const float* mW2 = (const float*)d_in[16];
  const float* mb2 = (const float*)d_in[17];
  float* out = (float*)d_out;

  const int N = in_sizes[0] / 64;      // 50000
  const int E = in_sizes[2];           // 800000

  char* ws = (char*)d_ws;
  size_t NB2 = (size_t)N * HD * 2;     // bf16 feature buffer
  u16* A       = (u16*)(ws);
  u16* B       = (u16*)(ws + NB2);
  char* q      = ws + 2 * NB2;
  // cntR and sums contiguous -> single memset
  int*   cntR  = (int*)q;              q += (size_t)NR * N * 4;
  float* sums  = (float*)q;            q += GD * HD * 4;
  u16* Wt      = (u16*)q;              q += (size_t)3 * HD * HD * 2;
  int2* csc    = (int2*)q;             q += (size_t)E * 8;
  int2* eidx   = (int2*)q;             q += (size_t)E * 8;
  int*  rank   = (int*)q;              q += (size_t)E * 4;
  float* dinv  = (float*)q;            q += (size_t)N * 4;
  int*   cursR = (int*)q;              q += (size_t)NR * N * 4;
  int*   offs  = (int*)q;              q += (size_t)(N + 2) * 4;
  int*   b32   = (int*)q;              q += (size_t)N * 4;
  int*   bsum  = (int*)q;              q += 64 * 4;

  dim3 blk(256);
  int gE  = (E + 255) / 256;
  int gN  = (N + 255) / 256;
  int nb1024 = (N + 1023) / 1024;

  hipMemsetAsync(cntR, 0, (size_t)NR * N * 4 + (size_t)GD * HD * 4, stream);
  convert_count_k<<<gE, blk, 0, stream>>>(ei, bt, eidx, b32, cntR, rank, E, N);
  scan1_k<<<nb1024, 1024, 0, stream>>>(cntR, offs, bsum, N, N);
  scan3curs_k<<<gN, blk, 0, stream>>>(offs, bsum, cntR, cursR, N, E, N, nb1024);
  fill_k<<<gE, blk, 0, stream>>>(eidx, ea, cursR, rank, csc, E, N);
  deg_k<<<gN, blk, 0, stream>>>(offs, csc, dinv, N);
  convw3_k<<<(3 * HD * HD + 255) / 256, blk, 0, stream>>>(W0, W1, W2, Wt);

  int gGemm = (N + 63) / 64;
  int gAgg  = (N * 16 + 255) / 256;

  // layer 0 (h0 construction fused into the GEMM A-fragment load)
  gemm0_k<<<gGemm, 256, 0, stream>>>(x, Wt, dinv, B, N);
  aggregate_k<<<gAgg, blk, 0, stream>>>(offs, csc, B, dinv, b0,
                                        bng, bnb, bnm, bnv, 1, A, N);
  // layer 1
  gemm_k<<<gGemm, 256, 0, stream>>>(A, Wt + HD * HD, dinv, B, N);
  aggregate_k<<<gAgg, blk, 0, stream>>>(offs, csc, B, dinv, b1,
                                        bng, bnb, bnm, bnv, 1, A, N);
  // layer 2 (no bn/relu)
  gemm_k<<<gGemm, 256, 0, stream>>>(A, Wt + 2 * HD * HD, dinv, B, N);
  aggregate_k<<<gAgg, blk, 0, stream>>>(offs, csc, B, dinv, b2,
                                        bng, bnb, bnm, bnv, 0, A, N);

  dim3 pgrid(32, GD);
  pool1_k<<<pgrid, 128, 0, stream>>>(A, b32, sums, N);
  mlp_k<<<GD, 128, 0, stream>>>(sums, b32, mW1, mb1, mW2, mb2, out, N);
}